// Round 4
// baseline (294.032 us; speedup 1.0000x reference)
//
#include <hip/hip_runtime.h>
#include <hip/hip_fp16.h>

#define NTOT   6422528   // 16*56*56*128
#define NPERB  401408    // 56*56*128
#define NQ4    100352    // NPERB/4
#define SATR   228       // SAT row stride in floats: 57*4
#define LOG2E  1.4426950408889634f

__device__ __forceinline__ float sigmoidf_fast(float x) {
    return __builtin_amdgcn_rcpf(1.f + __expf(-x));
}

// order-preserving float<->uint encoding (all-zero init valid for max)
__device__ __forceinline__ unsigned encf(float f) {
    unsigned u = __float_as_uint(f);
    return (u & 0x80000000u) ? ~u : (u | 0x80000000u);
}
__device__ __forceinline__ float decf(unsigned u) {
    return __uint_as_float((u & 0x80000000u) ? (u ^ 0x80000000u) : ~u);
}

__device__ __forceinline__ void kappa_consts(const float* kap, float* dcs) {
    float v[5]; float mean = 0.f;
    for (int s = 0; s < 5; s++) {
        float lr = 0.6931471805599453f * (float)(s + 1);
        float k_ = 1.f / (1.f + expf(-kap[s]));
        float lk = 1.f / (1.f + expf(-logf(k_ + 1e-7f)));
        v[s] = lk + lr; mean += v[s];
    }
    mean *= 0.2f; float nd = 0.f;
    for (int s = 0; s < 5; s++) { float d = v[s] - mean; dcs[s] = d; nd += d * d; }
    dcs[5] = sqrtf(nd);
}

struct ScaleU { int rb1, rb0; float xmch; };

// ---------- K0: per-sample min/max (XCD-affine; both as atomicMax) ----------
// 512 blocks x 256: b = p&15, chunk = p>>4 in [0,32). pmnn holds max(-x).
__global__ void k_minmax(const float4* __restrict__ x4,
                         unsigned* __restrict__ pmxu, unsigned* __restrict__ pmnn) {
    int p = blockIdx.x;
    int b = p & 15, chunk = p >> 4;
    const float4* base = x4 + b * NQ4 + chunk * 3136;
    float mx = -3.4e38f, mn = -3.4e38f;            // mn accumulates max(-x)
    for (int q = threadIdx.x; q < 3136; q += 256) {
        float4 v = base[q];
        mx = fmaxf(mx, fmaxf(fmaxf(v.x, v.y), fmaxf(v.z, v.w)));
        mn = fmaxf(mn, fmaxf(fmaxf(-v.x, -v.y), fmaxf(-v.z, -v.w)));
    }
    __shared__ float rmx[4], rmn[4];
    int lane = threadIdx.x & 63, w = threadIdx.x >> 6;
#pragma unroll
    for (int off = 32; off; off >>= 1) {
        mx = fmaxf(mx, __shfl_down(mx, off));
        mn = fmaxf(mn, __shfl_down(mn, off));
    }
    if (lane == 0) { rmx[w] = mx; rmn[w] = mn; }
    __syncthreads();
    if (threadIdx.x == 0) {
        mx = fmaxf(fmaxf(rmx[0], rmx[1]), fmaxf(rmx[2], rmx[3]));
        mn = fmaxf(fmaxf(rmn[0], rmn[1]), fmaxf(rmn[2], rmn[3]));
        atomicMax(&pmxu[b], encf(mx));
        atomicMax(&pmnn[b], encf(mn));
    }
}

// ---------- K1: SAT-in-LDS + gather + fused SE/mix tail ----------
// 512 blocks x 896 threads. b = p&15 (all 32 blocks of b on XCD b%8), cg = p>>4,
// channels [cg*4, cg*4+4). LDS SAT 57x57x4 fp32 = 51KB -> 2 blocks/CU, 28 waves/CU.
// Thread t: cc = t&3, jrow = (t%224)>>2 in [0,56), seg = t/224 in [0,4).
__launch_bounds__(896, 7)
__global__ void k_satg(const float* __restrict__ x,   const float* __restrict__ kap,
                       const float* __restrict__ gam, const float* __restrict__ bet,
                       const float* __restrict__ bnm, const float* __restrict__ bnv,
                       const unsigned* __restrict__ pmxu, const unsigned* __restrict__ pmnn,
                       float* __restrict__ sq, unsigned* __restrict__ cnt,
                       unsigned int* __restrict__ ABu,
                       const float* __restrict__ W1, const float* __restrict__ b1,
                       const float* __restrict__ W2, const float* __restrict__ b2,
                       float* __restrict__ out) {
    __shared__ float SATl[57 * SATR];     // (r*57 + col)*4 + cc : 51984 B
    __shared__ float tot[896];
    __shared__ float wsum[56];
    __shared__ float cst[9];              // d0..d4, nd, xm, xi, xm*xi
    __shared__ float sqz[128], hidl[16], excl[128];
    __shared__ int lastflag;

    const int p = blockIdx.x;
    const int b = p & 15, cg = p >> 4;
    const int c0 = cg * 4;
    const int t = threadIdx.x;
    const int cc = t & 3;
    const int jrow = (t % 224) >> 2;      // [0,56)
    const int seg = t / 224;              // [0,4)

    // guards: SAT row 0 and col 0
    if (t < 228) {
        SATl[t] = 0.f;                               // row 0
        SATl[(t >> 2) * SATR + (t & 3)] = 0.f;       // col 0
    }
    // block constants on two separate waves
    if (t == 0) {
        float mxv = decf(pmxu[b]);
        float mnv = -decf(pmnn[b]);
        float xi = 1.f / (mxv - mnv + 1e-7f);
        cst[6] = mnv; cst[7] = xi; cst[8] = mnv * xi;
    } else if (t == 64) {
        float d[6]; kappa_consts(kap, d);
#pragma unroll
        for (int s2 = 0; s2 < 6; s2++) cst[s2] = d[s2];
    }

    float v[14];
    // ---- A1: column prefix along i (4-way segmented) ----
    {
        const float* xp = x + b * NPERB + (seg * 14) * 7168 + jrow * 128 + c0 + cc;
        float acc = 0.f;
#pragma unroll
        for (int k = 0; k < 14; k++) { acc += xp[k * 7168]; v[k] = acc; }
        tot[t] = acc;
    }
    __syncthreads();   // S1
    {
        const int tj = jrow * 4 + cc;
        float base = 0.f;
        if (seg > 0) base += tot[tj];
        if (seg > 1) base += tot[224 + tj];
        if (seg > 2) base += tot[448 + tj];
#pragma unroll
        for (int k = 0; k < 14; k++)
            SATl[(seg * 14 + k + 1) * SATR + (jrow + 1) * 4 + cc] = base + v[k];
    }
    __syncthreads();   // S2: column-prefix SAT + cst ready

    // ---- A2: row prefix along j, in place (per-thread region) ----
    {
        const int colbase = (jrow + 1) * SATR + cc;
#pragma unroll
        for (int k = 0; k < 14; k++) v[k] = SATl[colbase + (seg * 14 + 1 + k) * 4];
#pragma unroll
        for (int k = 1; k < 14; k++) v[k] += v[k - 1];
        tot[t] = v[13];
    }
    __syncthreads();   // S3
    {
        const int tj = jrow * 4 + cc;
        float base = 0.f;
        if (seg > 0) base += tot[tj];
        if (seg > 1) base += tot[224 + tj];
        if (seg > 2) base += tot[448 + tj];
        const int colbase = (jrow + 1) * SATR + cc;
#pragma unroll
        for (int k = 0; k < 14; k++)
            SATl[colbase + (seg * 14 + 1 + k) * 4] = base + v[k];
    }
    __syncthreads();   // S4: full SAT ready

    // ---- A3: gather 14 pixels -> pack A/B -> ABu, accumulate squeeze ----
    float asum = 0.f;
    {
        const int i = jrow;
        const int j0 = seg * 14;
        const float xm = cst[6], xi = cst[7], xmxi = cst[8];
        const int ci = c0 + cc;
        const float g = gam[ci], be = bet[ci], bm = bnm[ci];
        const float rsv = rsqrtf(bnv[ci] + 1e-3f);
        const float A1c = g * rsv, A0c = be - g * bm * rsv;
        const float C1 = -A1c * (LOG2E * 0.1f);
        const float C0 = -A0c * LOG2E;
        const float d0 = cst[0], d1 = cst[1], d2 = cst[2], d3 = cst[3], d4 = cst[4], nd = cst[5];
        const float* sp = SATl + cc;

        auto mkU = [&](int hk) {
            ScaleU uu;
            int y1g = min(i + hk, 55) + 1;
            int y0g = max(i - hk + 1, 0);
            uu.rb1 = y1g * SATR; uu.rb0 = y0g * SATR;
            uu.xmch = xm * (float)(y1g - y0g);
            return uu;
        };
        const ScaleU u0 = mkU(1), u1 = mkU(2), u2 = mkU(4), u3 = mkU(8), u4 = mkU(16);

        auto meas = [&](int j, const ScaleU& uu, int hk) -> float {
            int x1g = min(j + hk, 55) + 1;
            int x0g = max(j - hk + 1, 0);
            float cw = (float)(x1g - x0g);
            int o1 = x1g << 2, o0 = x0g << 2;
            float s = sp[uu.rb1 + o1] - sp[uu.rb0 + o1] - sp[uu.rb1 + o0] + sp[uu.rb0 + o0];
            return __log2f(fmaxf((s - uu.xmch * cw) * xi, 0.f) + 1e-7f);
        };

        const float* xrow = x + b * NPERB + i * 7168 + ci;
        unsigned int* abrow = ABu + b * NPERB + i * 7168 + ci;
        for (int jj = 0; jj < 14; jj++) {
            int j = j0 + jj;
            float l0 = meas(j, u0, 1);
            float l1 = meas(j, u1, 2);
            float l2 = meas(j, u2, 4);
            float l3 = meas(j, u3, 8);
            float l4 = meas(j, u4, 16);
            float w2 = -2.f * l0 - l1 + l3 + 2.f * l4;
            asum += w2;
            float alphas = w2 * 0.1f;
            float mean = 0.2f * (l0 + l1 + l2 + l3 + l4);
            float a0 = l0 - mean, a1 = l1 - mean, a2 = l2 - mean, a3 = l3 - mean, a4 = l4 - mean;
            float na2  = a0 * a0 + a1 * a1 + a2 * a2 + a3 * a3 + a4 * a4;
            float adot = a0 * d0 + a1 * d1 + a2 * d2 + a3 * d3 + a4 * d4;
            float na = __builtin_amdgcn_sqrtf(na2);
            float cosv = (alphas * adot) * __builtin_amdgcn_rcpf(na * fabsf(alphas) * nd + 1e-7f);
            float sim = 0.5f * (cosv + 1.f);
            float sbn = __builtin_amdgcn_rcpf(1.f + exp2f(C1 * w2 + C0));
            float xs = fmaf(xrow[j * 128], xi, -xmxi);
            float A = sim * sbn;
            float B = (1.f - sim) * xs;
            abrow[j * 128] = __builtin_bit_cast(unsigned int, __floats2half2_rn(A, B));
        }
    }
    // squeeze: lanes with lane&3 == cc; 896 = 14 full waves
    asum += __shfl_down(asum, 32);
    asum += __shfl_down(asum, 16);
    asum += __shfl_down(asum, 8);
    asum += __shfl_down(asum, 4);
    if ((t & 63) < 4) wsum[(t >> 6) * 4 + (t & 3)] = asum;
    __syncthreads();
    if (t < 4) {
        float s = 0.f;
#pragma unroll
        for (int w = 0; w < 14; w++) s += wsum[w * 4 + t];
        atomicAdd(&sq[b * 128 + c0 + t], s * 0.1f);
    }

    // ---- ticket: 32nd arrival for sample b does SE + mix ----
    __threadfence();
    if (t == 0) lastflag = (atomicAdd(&cnt[b], 1u) == 31u) ? 1 : 0;
    __syncthreads();
    if (!lastflag) return;
    __threadfence();

    if (t < 128) sqz[t] = sq[b * 128 + t] * (1.f / 3136.f);
    __syncthreads();
    if (t < 16) {
        float acc = b1[t];
        for (int c2 = 0; c2 < 128; c2++) acc += sqz[c2] * W1[c2 * 16 + t];
        hidl[t] = fmaxf(acc, 0.f);
    }
    __syncthreads();
    if (t < 128) {
        float acc = b2[t];
#pragma unroll
        for (int h = 0; h < 16; h++) acc += hidl[h] * W2[h * 128 + t];
        excl[t] = sigmoidf_fast(acc);
    }
    __syncthreads();

    const uint4* ab4 = (const uint4*)ABu + b * NQ4;
    float4* out4 = (float4*)out + b * NQ4;
    for (int q = t; q < NQ4; q += 896) {
        int cb = (q & 31) << 2;
        uint4 u = ab4[q];
        float2 p0 = __half22float2(__builtin_bit_cast(__half2, u.x));
        float2 p1 = __half22float2(__builtin_bit_cast(__half2, u.y));
        float2 p2 = __half22float2(__builtin_bit_cast(__half2, u.z));
        float2 p3 = __half22float2(__builtin_bit_cast(__half2, u.w));
        out4[q] = make_float4(p0.x + p0.y * excl[cb],
                              p1.x + p1.y * excl[cb + 1],
                              p2.x + p2.y * excl[cb + 2],
                              p3.x + p3.y * excl[cb + 3]);
    }
}

extern "C" void kernel_launch(void* const* d_in, const int* in_sizes, int n_in,
                              void* d_out, int out_size, void* d_ws, size_t ws_size,
                              hipStream_t stream) {
    const float* x   = (const float*)d_in[0];
    const float* kap = (const float*)d_in[1];
    const float* W1  = (const float*)d_in[2];
    const float* b1  = (const float*)d_in[3];
    const float* W2  = (const float*)d_in[4];
    const float* b2  = (const float*)d_in[5];
    const float* gam = (const float*)d_in[6];
    const float* bet = (const float*)d_in[7];
    const float* bnm = (const float*)d_in[8];
    const float* bnv = (const float*)d_in[9];
    float* out = (float*)d_out;

    // ws: [sq 2048f][pmxu 16][pmnn 16][cnt 16][pad 16][ABu NTOT u32]
    float*    sq   = (float*)d_ws;
    unsigned* pmxu = (unsigned*)(sq + 2048);
    unsigned* pmnn = pmxu + 16;
    unsigned* cnt  = pmnn + 16;
    unsigned* ABu  = (unsigned*)(sq + 2112);     // byte offset 8448, 16B aligned

    hipMemsetAsync(d_ws, 0, 8448, stream);       // zeroes sq, pmxu, pmnn, cnt
    k_minmax<<<512, 256, 0, stream>>>((const float4*)x, pmxu, pmnn);
    k_satg<<<512, 896, 0, stream>>>(x, kap, gam, bet, bnm, bnv, pmxu, pmnn,
                                    sq, cnt, ABu, W1, b1, W2, b2, out);
}

// Round 5
// 154.559 us; speedup vs baseline: 1.9024x; 1.9024x over previous
//
#include <hip/hip_runtime.h>
#include <hip/hip_fp16.h>

#define NTOT   6422528   // 16*56*56*128
#define NPERB  401408    // 56*56*128
#define NQ4    100352    // NPERB/4
#define SATR   228       // SAT row stride in floats: 57*4
#define LOG2E  1.4426950408889634f

__device__ __forceinline__ float sigmoidf_fast(float x) {
    return __builtin_amdgcn_rcpf(1.f + __expf(-x));
}

// order-preserving float<->uint encoding (all-zero init valid for max)
__device__ __forceinline__ unsigned encf(float f) {
    unsigned u = __float_as_uint(f);
    return (u & 0x80000000u) ? ~u : (u | 0x80000000u);
}
__device__ __forceinline__ float decf(unsigned u) {
    return __uint_as_float((u & 0x80000000u) ? (u ^ 0x80000000u) : ~u);
}

__device__ __forceinline__ void kappa_consts(const float* kap, float* dcs) {
    float v[5]; float mean = 0.f;
    for (int s = 0; s < 5; s++) {
        float lr = 0.6931471805599453f * (float)(s + 1);
        float k_ = 1.f / (1.f + expf(-kap[s]));
        float lk = 1.f / (1.f + expf(-logf(k_ + 1e-7f)));
        v[s] = lk + lr; mean += v[s];
    }
    mean *= 0.2f; float nd = 0.f;
    for (int s = 0; s < 5; s++) { float d = v[s] - mean; dcs[s] = d; nd += d * d; }
    dcs[5] = sqrtf(nd);
}

struct ScaleU { int rb1, rb0; float xmch; };

// ---------- K0: per-sample min/max (XCD-affine; both via atomicMax) ----------
// 1024 blocks x 256 (4 blocks/CU, 16 waves): b = p&15, chunk = p>>4 in [0,64).
__global__ void k_minmax(const float4* __restrict__ x4,
                         unsigned* __restrict__ pmxu, unsigned* __restrict__ pmnn) {
    int p = blockIdx.x;
    int b = p & 15, chunk = p >> 4;
    const float4* base = x4 + b * NQ4 + chunk * 1568;
    float mx = -3.4e38f, mn = -3.4e38f;            // mn accumulates max(-x)
    for (int q = threadIdx.x; q < 1568; q += 256) {
        float4 v = base[q];
        mx = fmaxf(mx, fmaxf(fmaxf(v.x, v.y), fmaxf(v.z, v.w)));
        mn = fmaxf(mn, fmaxf(fmaxf(-v.x, -v.y), fmaxf(-v.z, -v.w)));
    }
    __shared__ float rmx[4], rmn[4];
    int lane = threadIdx.x & 63, w = threadIdx.x >> 6;
#pragma unroll
    for (int off = 32; off; off >>= 1) {
        mx = fmaxf(mx, __shfl_down(mx, off));
        mn = fmaxf(mn, __shfl_down(mn, off));
    }
    if (lane == 0) { rmx[w] = mx; rmn[w] = mn; }
    __syncthreads();
    if (threadIdx.x == 0) {
        mx = fmaxf(fmaxf(rmx[0], rmx[1]), fmaxf(rmx[2], rmx[3]));
        mn = fmaxf(fmaxf(rmn[0], rmn[1]), fmaxf(rmn[2], rmn[3]));
        atomicMax(&pmxu[b], encf(mx));
        atomicMax(&pmnn[b], encf(mn));
    }
}

// ---------- K1: SAT-in-LDS + gather ----------
// 512 blocks x 896 threads. b = p&15 (all 32 blocks of b on XCD b%8), cg = p>>4,
// channels [cg*4, cg*4+4). LDS SAT 57x57x4 fp32 = 51KB -> 2 blocks/CU, 28 waves/CU.
// Thread t: cc = t&3, jrow = (t%224)>>2 in [0,56), seg = t/224 in [0,4).
__launch_bounds__(896, 7)
__global__ void k_satg(const float* __restrict__ x,   const float* __restrict__ kap,
                       const float* __restrict__ gam, const float* __restrict__ bet,
                       const float* __restrict__ bnm, const float* __restrict__ bnv,
                       const unsigned* __restrict__ pmxu, const unsigned* __restrict__ pmnn,
                       float* __restrict__ sq, unsigned int* __restrict__ ABu) {
    __shared__ float SATl[57 * SATR];     // (r*57 + col)*4 + cc : 51984 B
    __shared__ float tot[896];
    __shared__ float wsum[56];
    __shared__ float cst[9];              // d0..d4, nd, xm, xi, xm*xi

    const int p = blockIdx.x;
    const int b = p & 15, cg = p >> 4;
    const int c0 = cg * 4;
    const int t = threadIdx.x;
    const int cc = t & 3;
    const int jrow = (t % 224) >> 2;      // [0,56)
    const int seg = t / 224;              // [0,4)

    // guards: SAT row 0 and col 0
    if (t < 228) {
        SATl[t] = 0.f;                               // row 0
        SATl[(t >> 2) * SATR + (t & 3)] = 0.f;       // col 0
    }
    // block constants on two separate waves
    if (t == 0) {
        float mxv = decf(pmxu[b]);
        float mnv = -decf(pmnn[b]);
        float xi = 1.f / (mxv - mnv + 1e-7f);
        cst[6] = mnv; cst[7] = xi; cst[8] = mnv * xi;
    } else if (t == 64) {
        float d[6]; kappa_consts(kap, d);
#pragma unroll
        for (int s2 = 0; s2 < 6; s2++) cst[s2] = d[s2];
    }

    float v[14];
    // ---- A1: column prefix along i (4-way segmented) ----
    {
        const float* xp = x + b * NPERB + (seg * 14) * 7168 + jrow * 128 + c0 + cc;
        float acc = 0.f;
#pragma unroll
        for (int k = 0; k < 14; k++) { acc += xp[k * 7168]; v[k] = acc; }
        tot[t] = acc;
    }
    __syncthreads();   // S1
    {
        const int tj = jrow * 4 + cc;
        float base = 0.f;
        if (seg > 0) base += tot[tj];
        if (seg > 1) base += tot[224 + tj];
        if (seg > 2) base += tot[448 + tj];
#pragma unroll
        for (int k = 0; k < 14; k++)
            SATl[(seg * 14 + k + 1) * SATR + (jrow + 1) * 4 + cc] = base + v[k];
    }
    __syncthreads();   // S2: column-prefix SAT + cst ready

    // ---- A2: row prefix along j, in place (per-thread region) ----
    {
        const int colbase = (jrow + 1) * SATR + cc;
#pragma unroll
        for (int k = 0; k < 14; k++) v[k] = SATl[colbase + (seg * 14 + 1 + k) * 4];
#pragma unroll
        for (int k = 1; k < 14; k++) v[k] += v[k - 1];
        tot[t] = v[13];
    }
    __syncthreads();   // S3
    {
        const int tj = jrow * 4 + cc;
        float base = 0.f;
        if (seg > 0) base += tot[tj];
        if (seg > 1) base += tot[224 + tj];
        if (seg > 2) base += tot[448 + tj];
        const int colbase = (jrow + 1) * SATR + cc;
#pragma unroll
        for (int k = 0; k < 14; k++)
            SATl[colbase + (seg * 14 + 1 + k) * 4] = base + v[k];
    }
    __syncthreads();   // S4: full SAT ready

    // ---- A3: gather 14 pixels -> pack A/B -> ABu, accumulate squeeze ----
    float asum = 0.f;
    {
        const int i = jrow;
        const int j0 = seg * 14;
        const float xm = cst[6], xi = cst[7], xmxi = cst[8];
        const int ci = c0 + cc;
        const float g = gam[ci], be = bet[ci], bm = bnm[ci];
        const float rsv = rsqrtf(bnv[ci] + 1e-3f);
        const float A1c = g * rsv, A0c = be - g * bm * rsv;
        const float C1 = -A1c * (LOG2E * 0.1f);
        const float C0 = -A0c * LOG2E;
        const float d0 = cst[0], d1 = cst[1], d2 = cst[2], d3 = cst[3], d4 = cst[4], nd = cst[5];
        const float* sp = SATl + cc;

        auto mkU = [&](int hk) {
            ScaleU uu;
            int y1g = min(i + hk, 55) + 1;
            int y0g = max(i - hk + 1, 0);
            uu.rb1 = y1g * SATR; uu.rb0 = y0g * SATR;
            uu.xmch = xm * (float)(y1g - y0g);
            return uu;
        };
        const ScaleU u0 = mkU(1), u1 = mkU(2), u2 = mkU(4), u3 = mkU(8), u4 = mkU(16);

        auto meas = [&](int j, const ScaleU& uu, int hk) -> float {
            int x1g = min(j + hk, 55) + 1;
            int x0g = max(j - hk + 1, 0);
            float cw = (float)(x1g - x0g);
            int o1 = x1g << 2, o0 = x0g << 2;
            float s = sp[uu.rb1 + o1] - sp[uu.rb0 + o1] - sp[uu.rb1 + o0] + sp[uu.rb0 + o0];
            // fmax((s - xmch*cw)*xi, 0) + eps  ==  fmax(fma(s - xmch*cw, xi, eps), eps)
            float t1 = fmaf(-uu.xmch, cw, s);
            return __log2f(fmaxf(fmaf(t1, xi, 1e-7f), 1e-7f));
        };

        const float* xrow = x + b * NPERB + i * 7168 + ci;
        unsigned int* abrow = ABu + b * NPERB + i * 7168 + ci;
        for (int jj = 0; jj < 14; jj++) {
            int j = j0 + jj;
            float l0 = meas(j, u0, 1);
            float l1 = meas(j, u1, 2);
            float l2 = meas(j, u2, 4);
            float l3 = meas(j, u3, 8);
            float l4 = meas(j, u4, 16);
            float w2 = -2.f * l0 - l1 + l3 + 2.f * l4;
            asum += w2;
            float alphas = w2 * 0.1f;
            float mean = 0.2f * (l0 + l1 + l2 + l3 + l4);
            float a0 = l0 - mean, a1 = l1 - mean, a2 = l2 - mean, a3 = l3 - mean, a4 = l4 - mean;
            float na2  = a0 * a0 + a1 * a1 + a2 * a2 + a3 * a3 + a4 * a4;
            float adot = a0 * d0 + a1 * d1 + a2 * d2 + a3 * d3 + a4 * d4;
            float na = __builtin_amdgcn_sqrtf(na2);
            float cosv = (alphas * adot) * __builtin_amdgcn_rcpf(na * fabsf(alphas) * nd + 1e-7f);
            float sim = 0.5f * (cosv + 1.f);
            float sbn = __builtin_amdgcn_rcpf(1.f + exp2f(C1 * w2 + C0));
            float xs = fmaf(xrow[j * 128], xi, -xmxi);
            float A = sim * sbn;
            float B = (1.f - sim) * xs;
            abrow[j * 128] = __builtin_bit_cast(unsigned int, __floats2half2_rn(A, B));
        }
    }
    // squeeze: reduce over lanes sharing cc; 896 = 14 full waves
    asum += __shfl_down(asum, 32);
    asum += __shfl_down(asum, 16);
    asum += __shfl_down(asum, 8);
    asum += __shfl_down(asum, 4);
    if ((t & 63) < 4) wsum[(t >> 6) * 4 + (t & 3)] = asum;
    __syncthreads();
    if (t < 4) {
        float s = 0.f;
#pragma unroll
        for (int w = 0; w < 14; w++) s += wsum[w * 4 + t];
        atomicAdd(&sq[b * 128 + c0 + t], s * 0.1f);
    }
}

// ---------- K2: SE + mix (XCD-affine: b = p&15, ABu read is L2-local) ----------
// 2048 blocks x 256: chunk = p>>4 in [0,128), 784 float4 per chunk.
__launch_bounds__(256)
__global__ void k_mix(const unsigned int* __restrict__ ABu, const float* __restrict__ sq,
                      const float* __restrict__ W1, const float* __restrict__ b1,
                      const float* __restrict__ W2, const float* __restrict__ b2,
                      float* __restrict__ out) {
    __shared__ float sqz[128];
    __shared__ float hid[16];
    __shared__ float exc[128];
    int p = blockIdx.x;
    int b = p & 15, chunk = p >> 4;
    int tid = threadIdx.x;
    if (tid < 128) sqz[tid] = sq[b * 128 + tid] * (1.f / 3136.f);
    __syncthreads();
    if (tid < 16) {
        float acc = b1[tid];
        for (int c2 = 0; c2 < 128; c2++) acc += sqz[c2] * W1[c2 * 16 + tid];
        hid[tid] = fmaxf(acc, 0.f);
    }
    __syncthreads();
    if (tid < 128) {
        float acc = b2[tid];
#pragma unroll
        for (int h = 0; h < 16; h++) acc += hid[h] * W2[h * 128 + tid];
        exc[tid] = sigmoidf_fast(acc);
    }
    __syncthreads();
    const uint4* ab4 = (const uint4*)ABu + b * NQ4 + chunk * 784;
    float4* out4 = (float4*)out + b * NQ4 + chunk * 784;
    for (int q = tid; q < 784; q += 256) {
        int cb = ((chunk * 784 + q) & 31) << 2;
        uint4 u = ab4[q];
        float2 p0 = __half22float2(__builtin_bit_cast(__half2, u.x));
        float2 p1 = __half22float2(__builtin_bit_cast(__half2, u.y));
        float2 p2 = __half22float2(__builtin_bit_cast(__half2, u.z));
        float2 p3 = __half22float2(__builtin_bit_cast(__half2, u.w));
        out4[q] = make_float4(p0.x + p0.y * exc[cb],
                              p1.x + p1.y * exc[cb + 1],
                              p2.x + p2.y * exc[cb + 2],
                              p3.x + p3.y * exc[cb + 3]);
    }
}

extern "C" void kernel_launch(void* const* d_in, const int* in_sizes, int n_in,
                              void* d_out, int out_size, void* d_ws, size_t ws_size,
                              hipStream_t stream) {
    const float* x   = (const float*)d_in[0];
    const float* kap = (const float*)d_in[1];
    const float* W1  = (const float*)d_in[2];
    const float* b1  = (const float*)d_in[3];
    const float* W2  = (const float*)d_in[4];
    const float* b2  = (const float*)d_in[5];
    const float* gam = (const float*)d_in[6];
    const float* bet = (const float*)d_in[7];
    const float* bnm = (const float*)d_in[8];
    const float* bnv = (const float*)d_in[9];
    float* out = (float*)d_out;

    // ws: [sq 2048f][pmxu 16][pmnn 16][pad 32][ABu NTOT u32]
    float*    sq   = (float*)d_ws;
    unsigned* pmxu = (unsigned*)(sq + 2048);
    unsigned* pmnn = pmxu + 16;
    unsigned* ABu  = (unsigned*)(sq + 2112);     // byte offset 8448, 16B aligned

    hipMemsetAsync(d_ws, 0, 8448, stream);       // zeroes sq, pmxu, pmnn
    k_minmax<<<1024, 256, 0, stream>>>((const float4*)x, pmxu, pmnn);
    k_satg<<<512, 896, 0, stream>>>(x, kap, gam, bet, bnm, bnv, pmxu, pmnn, sq, ABu);
    k_mix<<<2048, 256, 0, stream>>>(ABu, sq, W1, b1, W2, b2, out);
}